// Round 8
// baseline (1820.666 us; speedup 1.0000x reference)
//
#include <hip/hip_runtime.h>
#include <math.h>

// Problem constants (reference: B,T,D=16,512,256; HS=512, D_A=64, R=8)
#define BB 16
#define TT 512
#define DD 256
#define HS 512
#define DA 64
#define RR 8
#define G4H 2048   // 4*HS

typedef __attribute__((ext_vector_type(2))) float f2;

// -------- workspace layout (float offsets) --------
// s     :        0  (B*T*R =  65536)  <- k5's hbuf64 overlays this (dead by k4)
// e     :    65536
// inv   :   131072
// M     :   196608  (B*T*D   = 2097152)
// gates :  2293760  (B*T*4H  = 16777216)

// ============================================================
// K1: s[b,t,r] = tanh(x[b,t,:] @ w1 + b1) @ w2 + b2
// ============================================================
__global__ __launch_bounds__(256) void k1_score(
    const float* __restrict__ x, const float* __restrict__ w1,
    const float* __restrict__ b1, const float* __restrict__ w2,
    const float* __restrict__ b2, float* __restrict__ s_out) {
  const int wave = threadIdx.x >> 6;
  const int lane = threadIdx.x & 63;
  for (int i = 0; i < 4; ++i) {
    const int bt = blockIdx.x * 16 + wave * 4 + i;  // grid=512 -> 8192 bt
    const float* xr = x + bt * DD;
    float acc = b1[lane];
    #pragma unroll 4
    for (int d = 0; d < DD; ++d)
      acc = fmaf(xr[d], w1[d * DA + lane], acc);   // w1 coalesced over lanes
    const float a = tanhf(acc);
    #pragma unroll
    for (int r = 0; r < RR; ++r) {
      float v = a * w2[lane * RR + r];
      for (int off = 32; off > 0; off >>= 1) v += __shfl_xor(v, off);
      if (lane == 0) s_out[bt * RR + r] = v + b2[r];
    }
  }
}

// ============================================================
// K2: per (b,r): m=max_t s; e=exp(s-m); den=inclusive prefix sum
// ============================================================
__global__ __launch_bounds__(512) void k2_prefix(
    const float* __restrict__ s_in, float* __restrict__ e_out,
    float* __restrict__ inv_out) {
  const int b = blockIdx.x >> 3, r = blockIdx.x & 7;
  const int t = threadIdx.x;
  __shared__ float red[TT];
  __shared__ float buf[2][TT];
  const float v = s_in[(b * TT + t) * RR + r];
  red[t] = v;
  __syncthreads();
  for (int off = 256; off >= 1; off >>= 1) {
    if (t < off) red[t] = fmaxf(red[t], red[t + off]);
    __syncthreads();
  }
  const float m = red[0];
  const float e = expf(v - m);
  int p = 0;
  buf[0][t] = e;
  __syncthreads();
  for (int off = 1; off < TT; off <<= 1) {
    const float add = (t >= off) ? buf[p][t - off] : 0.f;
    buf[1 - p][t] = buf[p][t] + add;
    __syncthreads();
    p ^= 1;
  }
  const float den = buf[p][t];
  e_out[(b * TT + t) * RR + r] = e;
  inv_out[(b * TT + t) * RR + r] = 1.0f / den;
}

// ============================================================
// K3: M[b,t,d] = (1/R) * sum_r inv[t,r] * prefix_j<=t( e[j,r]*x[b,j,d] )
// ============================================================
__global__ __launch_bounds__(64) void k3_mix(
    const float* __restrict__ x, const float* __restrict__ e_in,
    const float* __restrict__ inv_in, float* __restrict__ Mout) {
  const int b = blockIdx.x >> 2;
  const int d = (blockIdx.x & 3) * 64 + threadIdx.x;
  __shared__ __align__(16) float el[TT * RR];
  __shared__ __align__(16) float il[TT * RR];
  for (int i = threadIdx.x * 4; i < TT * RR; i += 64 * 4) {
    *(float4*)&el[i] = *(const float4*)&e_in[b * TT * RR + i];
    *(float4*)&il[i] = *(const float4*)&inv_in[b * TT * RR + i];
  }
  __syncthreads();
  float4 c0 = {0.f, 0.f, 0.f, 0.f}, c1 = {0.f, 0.f, 0.f, 0.f};
  for (int t = 0; t < TT; ++t) {
    const float xv = x[(b * TT + t) * DD + d];
    const float4 e0 = *(const float4*)&el[t * RR];
    const float4 e1 = *(const float4*)&el[t * RR + 4];
    const float4 i0 = *(const float4*)&il[t * RR];
    const float4 i1 = *(const float4*)&il[t * RR + 4];
    c0.x = fmaf(e0.x, xv, c0.x); c0.y = fmaf(e0.y, xv, c0.y);
    c0.z = fmaf(e0.z, xv, c0.z); c0.w = fmaf(e0.w, xv, c0.w);
    c1.x = fmaf(e1.x, xv, c1.x); c1.y = fmaf(e1.y, xv, c1.y);
    c1.z = fmaf(e1.z, xv, c1.z); c1.w = fmaf(e1.w, xv, c1.w);
    float msum = c0.x * i0.x + c0.y * i0.y + c0.z * i0.z + c0.w * i0.w;
    msum += c1.x * i1.x + c1.y * i1.y + c1.z * i1.z + c1.w * i1.w;
    Mout[(b * TT + t) * DD + d] = msum * 0.125f;
  }
}

// ============================================================
// K4: gates = M(8192x256) @ W_ih(256x2048) + bias   (fp32 SGEMM)
// ============================================================
__global__ __launch_bounds__(256) void k4_gemm(
    const float* __restrict__ A, const float* __restrict__ Bw,
    const float* __restrict__ bias, float* __restrict__ C) {
  const int bn = blockIdx.x & 15;
  const int bm = blockIdx.x >> 4;
  const int tid = threadIdx.x;
  const int tx = tid & 15, ty = tid >> 4;
  __shared__ __align__(16) float As[16][132];
  __shared__ __align__(16) float Bs[16][132];
  const int row0 = bm * 128, col0 = bn * 128;

  float acc[2][4][2][4];
  #pragma unroll
  for (int a = 0; a < 2; ++a)
    #pragma unroll
    for (int i = 0; i < 4; ++i)
      #pragma unroll
      for (int q = 0; q < 2; ++q)
        #pragma unroll
        for (int j = 0; j < 4; ++j) acc[a][i][q][j] = 0.f;

  const int arow = tid >> 1, akc = (tid & 1) * 8;
  const int bkr = tid >> 4, bcc = (tid & 15) * 8;

  for (int k0 = 0; k0 < 256; k0 += 16) {
    const float4 a0 = *(const float4*)&A[(row0 + arow) * 256 + k0 + akc];
    const float4 a1 = *(const float4*)&A[(row0 + arow) * 256 + k0 + akc + 4];
    const float4 b0 = *(const float4*)&Bw[(k0 + bkr) * 2048 + col0 + bcc];
    const float4 b1 = *(const float4*)&Bw[(k0 + bkr) * 2048 + col0 + bcc + 4];
    __syncthreads();
    As[akc + 0][arow] = a0.x; As[akc + 1][arow] = a0.y;
    As[akc + 2][arow] = a0.z; As[akc + 3][arow] = a0.w;
    As[akc + 4][arow] = a1.x; As[akc + 5][arow] = a1.y;
    As[akc + 6][arow] = a1.z; As[akc + 7][arow] = a1.w;
    *(float4*)&Bs[bkr][bcc] = b0;
    *(float4*)&Bs[bkr][bcc + 4] = b1;
    __syncthreads();
    #pragma unroll
    for (int kk = 0; kk < 16; ++kk) {
      float av[8], bv[8];
      *(float4*)&av[0] = *(const float4*)&As[kk][ty * 4];
      *(float4*)&av[4] = *(const float4*)&As[kk][64 + ty * 4];
      *(float4*)&bv[0] = *(const float4*)&Bs[kk][tx * 4];
      *(float4*)&bv[4] = *(const float4*)&Bs[kk][64 + tx * 4];
      #pragma unroll
      for (int a = 0; a < 2; ++a)
        #pragma unroll
        for (int i = 0; i < 4; ++i)
          #pragma unroll
          for (int q = 0; q < 2; ++q)
            #pragma unroll
            for (int j = 0; j < 4; ++j)
              acc[a][i][q][j] = fmaf(av[a * 4 + i], bv[q * 4 + j], acc[a][i][q][j]);
    }
  }
  const float4 bias0 = *(const float4*)&bias[col0 + tx * 4];
  const float4 bias1 = *(const float4*)&bias[col0 + 64 + tx * 4];
  #pragma unroll
  for (int a = 0; a < 2; ++a)
    #pragma unroll
    for (int i = 0; i < 4; ++i) {
      const int row = row0 + a * 64 + ty * 4 + i;
      float4 v0, v1;
      v0.x = acc[a][i][0][0] + bias0.x; v0.y = acc[a][i][0][1] + bias0.y;
      v0.z = acc[a][i][0][2] + bias0.z; v0.w = acc[a][i][0][3] + bias0.w;
      v1.x = acc[a][i][1][0] + bias1.x; v1.y = acc[a][i][1][1] + bias1.y;
      v1.z = acc[a][i][1][2] + bias1.z; v1.w = acc[a][i][1][3] + bias1.w;
      *(float4*)&C[row * 2048 + col0 + tx * 4] = v0;
      *(float4*)&C[row * 2048 + col0 + 64 + tx * 4] = v1;
    }
}

// fast transcendentals: v_exp_f32 + v_rcp_f32 (~1e-6 err << 1.5e-2 tol)
__device__ __forceinline__ float fast_sigmoid(float x) {
  return __builtin_amdgcn_rcpf(1.f + __expf(-x));
}
__device__ __forceinline__ float fast_tanh(float x) {
  const float xc = fmaxf(x, -30.f);           // avoid inf*0 NaN
  const float e = __expf(-2.f * xc);
  return (1.f - e) * __builtin_amdgcn_rcpf(1.f + e);
}

__device__ __forceinline__ unsigned long long poll_ld(
    const unsigned long long* p) {
  return __hip_atomic_load(p, __ATOMIC_RELAXED, __HIP_MEMORY_SCOPE_AGENT);
}

// ============================================================
// K5 v8: 16 per-batch domains x 16 blocks (32 units), 512 thr.
// Fixes vs v7 (post-mortem: 3670 cyc/step, ~1500 unexplained ->
// vmcnt FIFO coupling of the gates HBM load into the poll):
//  (A) gates software-pipelined TWO steps ahead (g_cur/g_n1, issue
//      t+2): a poll's vmcnt drain only ever sees a >=1-step-old
//      gates load -> ~900cyc HBM latency leaves the critical path.
//  (B) raw `s_waitcnt lgkmcnt(0); s_barrier` instead of
//      __syncthreads: the compiler barrier drains vmcnt(0), which
//      would re-couple the just-issued gates load.
//  (C) sliding-window poll (4 outstanding same-address atomic
//      loads, check oldest): LLC sampled every ~25 cyc instead of
//      once per ~600cyc serial round trip.
//  (D) packed dot: wr as f2 pairs (i,f)/(g,o) -> v_pk_fma_f32,
//      halving dot VALU issue (512->256 cyc/SIMD/step).
// ============================================================
__global__ __launch_bounds__(512, 1) void k5_lstm(
    const float* __restrict__ gates, const float* __restrict__ whh,
    float* __restrict__ out, unsigned long long* hbuf) {
  const int s   = blockIdx.x & 15;       // unit-slice
  const int b   = blockIdx.x >> 4;       // batch = sync domain
  const int tid = threadIdx.x;           // 512 threads
  const int kq  = tid & 15;              // k-chunk: k in [kq*32, kq*32+32)
  const int cq  = tid >> 4;              // unit offset 0..31
  const int j0  = s * 32;
  const int unit = j0 + cq;

  __shared__ __align__(16) float Wl[256 * 128];  // staging, 128 KB
  __shared__ __align__(16) float hl[2][576];     // parity; chunk*36+pos

  // ---- stage W slice (coalesced) and gather into registers ----
  // wrA[kk]=(W[k][i-col],W[k][f-col]), wrB[kk]=(W[k][g-col],W[k][o-col])
  // of THIS thread's unit; volatile gather -> not rematerializable.
  f2 wrA[32], wrB[32];
  for (int rnd = 0; rnd < 2; ++rnd) {
    for (int i = tid * 4; i < 256 * 128; i += 512 * 4) {
      const int k = i >> 7, c = i & 127;   // Wl[k][c], c = gate*32 + uo
      *(float4*)&Wl[i] =
          *(const float4*)&whh[(rnd * 256 + k) * G4H + (c >> 5) * HS + j0 + (c & 31)];
    }
    __syncthreads();
    if ((kq >> 3) == rnd) {
      const int kb = (kq & 7) * 32;
      #pragma unroll
      for (int kk = 0; kk < 32; ++kk) {
        const int base = (kb + kk) * 128 + cq;
        wrA[kk].x = *(volatile const float*)&Wl[base];
        wrA[kk].y = *(volatile const float*)&Wl[base + 32];
        wrB[kk].x = *(volatile const float*)&Wl[base + 64];
        wrB[kk].y = *(volatile const float*)&Wl[base + 96];
      }
    }
    __syncthreads();
  }

  float c_reg = 0.f;   // cell state (lives in lanes kq==0; unit j0+cq)

  // gates pipeline: g_cur = row t, g_n1 = row t+1 (kq==0 lanes only)
  float4 g_cur = {0, 0, 0, 0}, g_n1 = {0, 0, 0, 0};
  const float* gbase = gates + (long)b * TT * G4H + unit;
  if (kq == 0) {
    g_cur.x = gbase[0];            g_cur.y = gbase[HS];
    g_cur.z = gbase[2 * HS];       g_cur.w = gbase[3 * HS];
    const float* g1 = gbase + G4H;
    g_n1.x = g1[0];                g_n1.y = g1[HS];
    g_n1.z = g1[2 * HS];           g_n1.w = g1[3 * HS];
  }

  for (int t = 0; t < TT; ++t) {
    const int par = t & 1;
    if (t > 0) {
      // sliding-window poll of my own unit's packet (tag >= t):
      // 4 outstanding relaxed loads; check oldest; refill one/iter.
      const unsigned long long* ha =
          hbuf + (((t - 1) & 1) * BB + b) * HS + tid;
      unsigned long long p0 = poll_ld(ha), p1 = poll_ld(ha);
      unsigned long long p2 = poll_ld(ha), p3 = poll_ld(ha);
      for (;;) {
        if ((unsigned)(p0 >> 32) >= (unsigned)t) break;
        p0 = p1; p1 = p2; p2 = p3; p3 = poll_ld(ha);
      }
      hl[par][(tid >> 5) * 36 + (tid & 31)] = __uint_as_float((unsigned)p0);
    }
    // issue gates row t+2 (post-poll: next poll sees it >=1 step old)
    float4 g_n2 = {0, 0, 0, 0};
    if (kq == 0) {
      const int tn = (t + 2 < TT) ? t + 2 : TT - 1;
      const float* g2 = gbase + (long)tn * G4H;
      g_n2.x = g2[0];        g_n2.y = g2[HS];
      g_n2.z = g2[2 * HS];   g_n2.w = g2[3 * HS];
    }
    // raw barrier: order LDS (hl writes) only; do NOT drain vmcnt
    __asm__ __volatile__("s_waitcnt lgkmcnt(0)\ns_barrier" ::: "memory");
    f2 acc01 = {0.f, 0.f}, acc23 = {0.f, 0.f};
    if (t > 0) {
      const float* hb = &hl[par][kq * 36];
      #pragma unroll
      for (int i = 0; i < 8; ++i) {
        const float4 h4 = *(const float4*)(hb + i * 4);
        const f2 hx = {h4.x, h4.x}, hy = {h4.y, h4.y};
        const f2 hz = {h4.z, h4.z}, hw = {h4.w, h4.w};
        acc01 += wrA[i * 4 + 0] * hx;  acc23 += wrB[i * 4 + 0] * hx;
        acc01 += wrA[i * 4 + 1] * hy;  acc23 += wrB[i * 4 + 1] * hy;
        acc01 += wrA[i * 4 + 2] * hz;  acc23 += wrB[i * 4 + 2] * hz;
        acc01 += wrA[i * 4 + 3] * hw;  acc23 += wrB[i * 4 + 3] * hw;
      }
    }
    // butterfly over the 16 kq lanes (in-wave: group = 16 consecutive)
    #pragma unroll
    for (int off = 1; off <= 8; off <<= 1) {
      acc01.x += __shfl_xor(acc01.x, off);
      acc01.y += __shfl_xor(acc01.y, off);
      acc23.x += __shfl_xor(acc23.x, off);
      acc23.y += __shfl_xor(acc23.y, off);
    }
    // fused epilogue + publish: lane kq==0 has full (i,f,g,o) of unit
    if (kq == 0) {
      const float I = fast_sigmoid(acc01.x + g_cur.x);
      const float F = fast_sigmoid(acc01.y + g_cur.y);
      const float G = fast_tanh(acc23.x + g_cur.z);
      const float O = fast_sigmoid(acc23.y + g_cur.w);
      c_reg = F * c_reg + I * G;
      const float h = O * fast_tanh(c_reg);
      const unsigned long long pkt =
          ((unsigned long long)(unsigned)(t + 1) << 32) |
          (unsigned long long)__float_as_uint(h);
      __hip_atomic_store(&hbuf[(par * BB + b) * HS + unit], pkt,
                         __ATOMIC_RELAXED, __HIP_MEMORY_SCOPE_AGENT);
      out[((long)b * TT + t) * HS + unit] = h;   // hidden_seq (post-publish)
      if (t == TT - 1) {
        out[(long)BB * TT * HS + b * HS + unit] = h;               // h_t
        out[(long)BB * TT * HS + BB * HS + b * HS + unit] = c_reg; // c_t
      }
    }
    g_cur = g_n1;
    g_n1 = g_n2;
  }
}

// ============================================================
extern "C" void kernel_launch(void* const* d_in, const int* in_sizes, int n_in,
                              void* d_out, int out_size, void* d_ws,
                              size_t ws_size, hipStream_t stream) {
  const float* x    = (const float*)d_in[0];
  const float* w1   = (const float*)d_in[1];
  const float* b1   = (const float*)d_in[2];
  const float* w2   = (const float*)d_in[3];
  const float* b2   = (const float*)d_in[4];
  const float* wih  = (const float*)d_in[5];
  const float* whh  = (const float*)d_in[6];
  const float* bias = (const float*)d_in[7];
  float* out = (float*)d_out;

  float* ws = (float*)d_ws;
  float* s_buf  = ws;                    // 65536 floats; dead after k2
  float* e_buf  = ws + 65536;
  float* i_buf  = ws + 131072;
  float* M_buf  = ws + 196608;
  float* g_buf  = ws + 2293760;
  // hbuf64 overlays the s region (2*16*512 uint64 = 128 KB <= 256 KB)
  unsigned long long* hbuf64 = (unsigned long long*)ws;

  k1_score<<<512, 256, 0, stream>>>(x, w1, b1, w2, b2, s_buf);
  k2_prefix<<<BB * RR, 512, 0, stream>>>(s_buf, e_buf, i_buf);
  k3_mix<<<64, 64, 0, stream>>>(x, e_buf, i_buf, M_buf);
  k4_gemm<<<64 * 16, 256, 0, stream>>>(M_buf, wih, bias, g_buf);
  // zero the packet tags (ws re-poisoned 0xAA each call; 0xAAAAAAAA > any t
  // would instantly satisfy polls). Stream-ordered after k2's s_buf reads.
  hipMemsetAsync(hbuf64, 0, 2 * BB * HS * sizeof(unsigned long long), stream);
  k5_lstm<<<256, 512, 0, stream>>>(g_buf, whh, out, hbuf64);
}

// Round 9
// 1161.985 us; speedup vs baseline: 1.5669x; 1.5669x over previous
//
#include <hip/hip_runtime.h>
#include <math.h>

// Problem constants (reference: B,T,D=16,512,256; HS=512, D_A=64, R=8)
#define BB 16
#define TT 512
#define DD 256
#define HS 512
#define DA 64
#define RR 8
#define G4H 2048   // 4*HS

typedef __attribute__((ext_vector_type(2))) float f2;

// -------- workspace layout (float offsets) --------
// s     :        0  (B*T*R =  65536)  <- k5's hbuf64 overlays this (dead by k4)
// e     :    65536
// inv   :   131072
// M     :   196608  (B*T*D   = 2097152)
// gates :  2293760  (B*T*4H  = 16777216)

// ============================================================
// K1: s[b,t,r] = tanh(x[b,t,:] @ w1 + b1) @ w2 + b2
// ============================================================
__global__ __launch_bounds__(256) void k1_score(
    const float* __restrict__ x, const float* __restrict__ w1,
    const float* __restrict__ b1, const float* __restrict__ w2,
    const float* __restrict__ b2, float* __restrict__ s_out) {
  const int wave = threadIdx.x >> 6;
  const int lane = threadIdx.x & 63;
  for (int i = 0; i < 4; ++i) {
    const int bt = blockIdx.x * 16 + wave * 4 + i;  // grid=512 -> 8192 bt
    const float* xr = x + bt * DD;
    float acc = b1[lane];
    #pragma unroll 4
    for (int d = 0; d < DD; ++d)
      acc = fmaf(xr[d], w1[d * DA + lane], acc);   // w1 coalesced over lanes
    const float a = tanhf(acc);
    #pragma unroll
    for (int r = 0; r < RR; ++r) {
      float v = a * w2[lane * RR + r];
      for (int off = 32; off > 0; off >>= 1) v += __shfl_xor(v, off);
      if (lane == 0) s_out[bt * RR + r] = v + b2[r];
    }
  }
}

// ============================================================
// K2: per (b,r): m=max_t s; e=exp(s-m); den=inclusive prefix sum
// ============================================================
__global__ __launch_bounds__(512) void k2_prefix(
    const float* __restrict__ s_in, float* __restrict__ e_out,
    float* __restrict__ inv_out) {
  const int b = blockIdx.x >> 3, r = blockIdx.x & 7;
  const int t = threadIdx.x;
  __shared__ float red[TT];
  __shared__ float buf[2][TT];
  const float v = s_in[(b * TT + t) * RR + r];
  red[t] = v;
  __syncthreads();
  for (int off = 256; off >= 1; off >>= 1) {
    if (t < off) red[t] = fmaxf(red[t], red[t + off]);
    __syncthreads();
  }
  const float m = red[0];
  const float e = expf(v - m);
  int p = 0;
  buf[0][t] = e;
  __syncthreads();
  for (int off = 1; off < TT; off <<= 1) {
    const float add = (t >= off) ? buf[p][t - off] : 0.f;
    buf[1 - p][t] = buf[p][t] + add;
    __syncthreads();
    p ^= 1;
  }
  const float den = buf[p][t];
  e_out[(b * TT + t) * RR + r] = e;
  inv_out[(b * TT + t) * RR + r] = 1.0f / den;
}

// ============================================================
// K3: M[b,t,d] = (1/R) * sum_r inv[t,r] * prefix_j<=t( e[j,r]*x[b,j,d] )
// ============================================================
__global__ __launch_bounds__(64) void k3_mix(
    const float* __restrict__ x, const float* __restrict__ e_in,
    const float* __restrict__ inv_in, float* __restrict__ Mout) {
  const int b = blockIdx.x >> 2;
  const int d = (blockIdx.x & 3) * 64 + threadIdx.x;
  __shared__ __align__(16) float el[TT * RR];
  __shared__ __align__(16) float il[TT * RR];
  for (int i = threadIdx.x * 4; i < TT * RR; i += 64 * 4) {
    *(float4*)&el[i] = *(const float4*)&e_in[b * TT * RR + i];
    *(float4*)&il[i] = *(const float4*)&inv_in[b * TT * RR + i];
  }
  __syncthreads();
  float4 c0 = {0.f, 0.f, 0.f, 0.f}, c1 = {0.f, 0.f, 0.f, 0.f};
  for (int t = 0; t < TT; ++t) {
    const float xv = x[(b * TT + t) * DD + d];
    const float4 e0 = *(const float4*)&el[t * RR];
    const float4 e1 = *(const float4*)&el[t * RR + 4];
    const float4 i0 = *(const float4*)&il[t * RR];
    const float4 i1 = *(const float4*)&il[t * RR + 4];
    c0.x = fmaf(e0.x, xv, c0.x); c0.y = fmaf(e0.y, xv, c0.y);
    c0.z = fmaf(e0.z, xv, c0.z); c0.w = fmaf(e0.w, xv, c0.w);
    c1.x = fmaf(e1.x, xv, c1.x); c1.y = fmaf(e1.y, xv, c1.y);
    c1.z = fmaf(e1.z, xv, c1.z); c1.w = fmaf(e1.w, xv, c1.w);
    float msum = c0.x * i0.x + c0.y * i0.y + c0.z * i0.z + c0.w * i0.w;
    msum += c1.x * i1.x + c1.y * i1.y + c1.z * i1.z + c1.w * i1.w;
    Mout[(b * TT + t) * DD + d] = msum * 0.125f;
  }
}

// ============================================================
// K4: gates = M(8192x256) @ W_ih(256x2048) + bias   (fp32 SGEMM)
// ============================================================
__global__ __launch_bounds__(256) void k4_gemm(
    const float* __restrict__ A, const float* __restrict__ Bw,
    const float* __restrict__ bias, float* __restrict__ C) {
  const int bn = blockIdx.x & 15;
  const int bm = blockIdx.x >> 4;
  const int tid = threadIdx.x;
  const int tx = tid & 15, ty = tid >> 4;
  __shared__ __align__(16) float As[16][132];
  __shared__ __align__(16) float Bs[16][132];
  const int row0 = bm * 128, col0 = bn * 128;

  float acc[2][4][2][4];
  #pragma unroll
  for (int a = 0; a < 2; ++a)
    #pragma unroll
    for (int i = 0; i < 4; ++i)
      #pragma unroll
      for (int q = 0; q < 2; ++q)
        #pragma unroll
        for (int j = 0; j < 4; ++j) acc[a][i][q][j] = 0.f;

  const int arow = tid >> 1, akc = (tid & 1) * 8;
  const int bkr = tid >> 4, bcc = (tid & 15) * 8;

  for (int k0 = 0; k0 < 256; k0 += 16) {
    const float4 a0 = *(const float4*)&A[(row0 + arow) * 256 + k0 + akc];
    const float4 a1 = *(const float4*)&A[(row0 + arow) * 256 + k0 + akc + 4];
    const float4 b0 = *(const float4*)&Bw[(k0 + bkr) * 2048 + col0 + bcc];
    const float4 b1 = *(const float4*)&Bw[(k0 + bkr) * 2048 + col0 + bcc + 4];
    __syncthreads();
    As[akc + 0][arow] = a0.x; As[akc + 1][arow] = a0.y;
    As[akc + 2][arow] = a0.z; As[akc + 3][arow] = a0.w;
    As[akc + 4][arow] = a1.x; As[akc + 5][arow] = a1.y;
    As[akc + 6][arow] = a1.z; As[akc + 7][arow] = a1.w;
    *(float4*)&Bs[bkr][bcc] = b0;
    *(float4*)&Bs[bkr][bcc + 4] = b1;
    __syncthreads();
    #pragma unroll
    for (int kk = 0; kk < 16; ++kk) {
      float av[8], bv[8];
      *(float4*)&av[0] = *(const float4*)&As[kk][ty * 4];
      *(float4*)&av[4] = *(const float4*)&As[kk][64 + ty * 4];
      *(float4*)&bv[0] = *(const float4*)&Bs[kk][tx * 4];
      *(float4*)&bv[4] = *(const float4*)&Bs[kk][64 + tx * 4];
      #pragma unroll
      for (int a = 0; a < 2; ++a)
        #pragma unroll
        for (int i = 0; i < 4; ++i)
          #pragma unroll
          for (int q = 0; q < 2; ++q)
            #pragma unroll
            for (int j = 0; j < 4; ++j)
              acc[a][i][q][j] = fmaf(av[a * 4 + i], bv[q * 4 + j], acc[a][i][q][j]);
    }
  }
  const float4 bias0 = *(const float4*)&bias[col0 + tx * 4];
  const float4 bias1 = *(const float4*)&bias[col0 + 64 + tx * 4];
  #pragma unroll
  for (int a = 0; a < 2; ++a)
    #pragma unroll
    for (int i = 0; i < 4; ++i) {
      const int row = row0 + a * 64 + ty * 4 + i;
      float4 v0, v1;
      v0.x = acc[a][i][0][0] + bias0.x; v0.y = acc[a][i][0][1] + bias0.y;
      v0.z = acc[a][i][0][2] + bias0.z; v0.w = acc[a][i][0][3] + bias0.w;
      v1.x = acc[a][i][1][0] + bias1.x; v1.y = acc[a][i][1][1] + bias1.y;
      v1.z = acc[a][i][1][2] + bias1.z; v1.w = acc[a][i][1][3] + bias1.w;
      *(float4*)&C[row * 2048 + col0 + tx * 4] = v0;
      *(float4*)&C[row * 2048 + col0 + 64 + tx * 4] = v1;
    }
}

// fast transcendentals: v_exp_f32 + v_rcp_f32 (~1e-6 err << 1.5e-2 tol)
__device__ __forceinline__ float fast_sigmoid(float x) {
  return __builtin_amdgcn_rcpf(1.f + __expf(-x));
}
__device__ __forceinline__ float fast_tanh(float x) {
  const float xc = fmaxf(x, -30.f);           // avoid inf*0 NaN
  const float e = __expf(-2.f * xc);
  return (1.f - e) * __builtin_amdgcn_rcpf(1.f + e);
}

__device__ __forceinline__ unsigned long long poll_ld(
    const unsigned long long* p) {
  return __hip_atomic_load(p, __ATOMIC_RELAXED, __HIP_MEMORY_SCOPE_AGENT);
}

// ============================================================
// K5 v9: 16 per-batch domains x 16 blocks (32 units), 512 thr.
// v8 post-mortem: the sliding-window poll (4 outstanding, refill
// 1/iter) multiplied chip-wide LLC poll traffic ~5x (131K threads
// x 1 load/~150cyc ~ 7 TB/s of coherent 8B reads) -> fabric
// saturation: dur 894->1584us, VALUBusy 32->22%, 32ms outliers.
// Poll LATENCY was never binding; poll BANDWIDTH became binding.
// v9 = v8 with the poll reverted to v7's serial one-outstanding
// form, KEEPING the three sound changes:
//  (A) gates software-pipelined TWO steps ahead: every vmcnt(0)
//      drain inside the poll only sees a >=1-step-old gates load,
//      so the ~900cyc HBM latency stays off the critical path
//      (this was v7's unexplained ~1500cyc/step).
//  (B) raw `s_waitcnt lgkmcnt(0); s_barrier` (no vmcnt drain at
//      the barrier -> in-flight gates loads stay in flight).
//  (D) packed f2 dot -> v_pk_fma_f32, halving dot VALU issue.
// ============================================================
__global__ __launch_bounds__(512, 1) void k5_lstm(
    const float* __restrict__ gates, const float* __restrict__ whh,
    float* __restrict__ out, unsigned long long* hbuf) {
  const int s   = blockIdx.x & 15;       // unit-slice
  const int b   = blockIdx.x >> 4;       // batch = sync domain
  const int tid = threadIdx.x;           // 512 threads
  const int kq  = tid & 15;              // k-chunk: k in [kq*32, kq*32+32)
  const int cq  = tid >> 4;              // unit offset 0..31
  const int j0  = s * 32;
  const int unit = j0 + cq;

  __shared__ __align__(16) float Wl[256 * 128];  // staging, 128 KB
  __shared__ __align__(16) float hl[2][576];     // parity; chunk*36+pos

  // ---- stage W slice (coalesced) and gather into registers ----
  // wrA[kk]=(W[k][i-col],W[k][f-col]), wrB[kk]=(W[k][g-col],W[k][o-col])
  // of THIS thread's unit; volatile gather -> not rematerializable.
  f2 wrA[32], wrB[32];
  for (int rnd = 0; rnd < 2; ++rnd) {
    for (int i = tid * 4; i < 256 * 128; i += 512 * 4) {
      const int k = i >> 7, c = i & 127;   // Wl[k][c], c = gate*32 + uo
      *(float4*)&Wl[i] =
          *(const float4*)&whh[(rnd * 256 + k) * G4H + (c >> 5) * HS + j0 + (c & 31)];
    }
    __syncthreads();
    if ((kq >> 3) == rnd) {
      const int kb = (kq & 7) * 32;
      #pragma unroll
      for (int kk = 0; kk < 32; ++kk) {
        const int base = (kb + kk) * 128 + cq;
        wrA[kk].x = *(volatile const float*)&Wl[base];
        wrA[kk].y = *(volatile const float*)&Wl[base + 32];
        wrB[kk].x = *(volatile const float*)&Wl[base + 64];
        wrB[kk].y = *(volatile const float*)&Wl[base + 96];
      }
    }
    __syncthreads();
  }

  float c_reg = 0.f;   // cell state (lives in lanes kq==0; unit j0+cq)

  // gates pipeline: g_cur = row t, g_n1 = row t+1 (kq==0 lanes only)
  float4 g_cur = {0, 0, 0, 0}, g_n1 = {0, 0, 0, 0};
  const float* gbase = gates + (long)b * TT * G4H + unit;
  if (kq == 0) {
    g_cur.x = gbase[0];            g_cur.y = gbase[HS];
    g_cur.z = gbase[2 * HS];       g_cur.w = gbase[3 * HS];
    const float* g1 = gbase + G4H;
    g_n1.x = g1[0];                g_n1.y = g1[HS];
    g_n1.z = g1[2 * HS];           g_n1.w = g1[3 * HS];
  }

  for (int t = 0; t < TT; ++t) {
    const int par = t & 1;
    if (t > 0) {
      // serial poll (ONE outstanding load per thread): my unit's
      // packet for step t-1 carries tag >= t. ~600cyc LLC round trip
      // per sample; chip-wide poll traffic stays ~1.7 TB/s (v7 level).
      const unsigned long long* ha =
          hbuf + (((t - 1) & 1) * BB + b) * HS + tid;
      unsigned long long pkt;
      do {
        pkt = poll_ld(ha);
      } while ((unsigned)(pkt >> 32) < (unsigned)t);
      hl[par][(tid >> 5) * 36 + (tid & 31)] = __uint_as_float((unsigned)pkt);
    }
    // issue gates row t+2 (textually post-poll; by the time the NEXT
    // poll drains vmcnt(0), this load is a full step (~1us) old)
    float4 g_n2 = {0, 0, 0, 0};
    if (kq == 0) {
      const int tn = (t + 2 < TT) ? t + 2 : TT - 1;
      const float* g2 = gbase + (long)tn * G4H;
      g_n2.x = g2[0];        g_n2.y = g2[HS];
      g_n2.z = g2[2 * HS];   g_n2.w = g2[3 * HS];
    }
    // raw barrier: order LDS (hl writes) only; do NOT drain vmcnt
    __asm__ __volatile__("s_waitcnt lgkmcnt(0)\ns_barrier" ::: "memory");
    f2 acc01 = {0.f, 0.f}, acc23 = {0.f, 0.f};
    if (t > 0) {
      const float* hb = &hl[par][kq * 36];
      #pragma unroll
      for (int i = 0; i < 8; ++i) {
        const float4 h4 = *(const float4*)(hb + i * 4);
        const f2 hx = {h4.x, h4.x}, hy = {h4.y, h4.y};
        const f2 hz = {h4.z, h4.z}, hw = {h4.w, h4.w};
        acc01 += wrA[i * 4 + 0] * hx;  acc23 += wrB[i * 4 + 0] * hx;
        acc01 += wrA[i * 4 + 1] * hy;  acc23 += wrB[i * 4 + 1] * hy;
        acc01 += wrA[i * 4 + 2] * hz;  acc23 += wrB[i * 4 + 2] * hz;
        acc01 += wrA[i * 4 + 3] * hw;  acc23 += wrB[i * 4 + 3] * hw;
      }
    }
    // butterfly over the 16 kq lanes (in-wave: group = 16 consecutive)
    #pragma unroll
    for (int off = 1; off <= 8; off <<= 1) {
      acc01.x += __shfl_xor(acc01.x, off);
      acc01.y += __shfl_xor(acc01.y, off);
      acc23.x += __shfl_xor(acc23.x, off);
      acc23.y += __shfl_xor(acc23.y, off);
    }
    // fused epilogue + publish: lane kq==0 has full (i,f,g,o) of unit
    if (kq == 0) {
      const float I = fast_sigmoid(acc01.x + g_cur.x);
      const float F = fast_sigmoid(acc01.y + g_cur.y);
      const float G = fast_tanh(acc23.x + g_cur.z);
      const float O = fast_sigmoid(acc23.y + g_cur.w);
      c_reg = F * c_reg + I * G;
      const float h = O * fast_tanh(c_reg);
      const unsigned long long pkt =
          ((unsigned long long)(unsigned)(t + 1) << 32) |
          (unsigned long long)__float_as_uint(h);
      __hip_atomic_store(&hbuf[(par * BB + b) * HS + unit], pkt,
                         __ATOMIC_RELAXED, __HIP_MEMORY_SCOPE_AGENT);
      out[((long)b * TT + t) * HS + unit] = h;   // hidden_seq (post-publish)
      if (t == TT - 1) {
        out[(long)BB * TT * HS + b * HS + unit] = h;               // h_t
        out[(long)BB * TT * HS + BB * HS + b * HS + unit] = c_reg; // c_t
      }
    }
    g_cur = g_n1;
    g_n1 = g_n2;
  }
}

// ============================================================
extern "C" void kernel_launch(void* const* d_in, const int* in_sizes, int n_in,
                              void* d_out, int out_size, void* d_ws,
                              size_t ws_size, hipStream_t stream) {
  const float* x    = (const float*)d_in[0];
  const float* w1   = (const float*)d_in[1];
  const float* b1   = (const float*)d_in[2];
  const float* w2   = (const float*)d_in[3];
  const float* b2   = (const float*)d_in[4];
  const float* wih  = (const float*)d_in[5];
  const float* whh  = (const float*)d_in[6];
  const float* bias = (const float*)d_in[7];
  float* out = (float*)d_out;

  float* ws = (float*)d_ws;
  float* s_buf  = ws;                    // 65536 floats; dead after k2
  float* e_buf  = ws + 65536;
  float* i_buf  = ws + 131072;
  float* M_buf  = ws + 196608;
  float* g_buf  = ws + 2293760;
  // hbuf64 overlays the s region (2*16*512 uint64 = 128 KB <= 256 KB)
  unsigned long long* hbuf64 = (unsigned long long*)ws;

  k1_score<<<512, 256, 0, stream>>>(x, w1, b1, w2, b2, s_buf);
  k2_prefix<<<BB * RR, 512, 0, stream>>>(s_buf, e_buf, i_buf);
  k3_mix<<<64, 64, 0, stream>>>(x, e_buf, i_buf, M_buf);
  k4_gemm<<<64 * 16, 256, 0, stream>>>(M_buf, wih, bias, g_buf);
  // zero the packet tags (ws re-poisoned 0xAA each call; 0xAAAAAAAA > any t
  // would instantly satisfy polls). Stream-ordered after k2's s_buf reads.
  hipMemsetAsync(hbuf64, 0, 2 * BB * HS * sizeof(unsigned long long), stream);
  k5_lstm<<<256, 512, 0, stream>>>(g_buf, whh, out, hbuf64);
}

// Round 10
// 1154.399 us; speedup vs baseline: 1.5772x; 1.0066x over previous
//
#include <hip/hip_runtime.h>
#include <math.h>

// Problem constants (reference: B,T,D=16,512,256; HS=512, D_A=64, R=8)
#define BB 16
#define TT 512
#define DD 256
#define HS 512
#define DA 64
#define RR 8
#define G4H 2048   // 4*HS

typedef __attribute__((ext_vector_type(2))) float f2;
typedef __attribute__((ext_vector_type(8))) short bf16x8;
typedef __attribute__((ext_vector_type(4))) float f32x4;
typedef unsigned short ushort_t;

// -------- workspace layout (float offsets) --------
// s     :        0  (B*T*R = 65536)   <- k5's hbuf64 overlays (dead by k4)
// e     :    65536
// inv   :   131072
// Mb    :   196608  (bf16, B*T*D = 2,097,152 ushorts = 1,048,576 floats)
// Wtb   :  1245184  (bf16, 2048x256  =   524,288 ushorts =   262,144 floats)
// gates :  2293760  (B*T*4H = 16,777,216 floats)

__device__ __forceinline__ ushort_t f2bf(float f) {
  const unsigned u = __float_as_uint(f);
  return (ushort_t)((u + 0x7FFFu + ((u >> 16) & 1u)) >> 16);  // RNE
}

// ============================================================
// K0w: Wtb[n][k] = bf16(W_ih[k][n])   (2048x256 <- 256x2048)
// ============================================================
__global__ __launch_bounds__(256) void k0w_transpose(
    const float* __restrict__ W, ushort_t* __restrict__ Wt) {
  __shared__ float tl[64][65];
  const int kb = (blockIdx.x & 3) * 64;   // 256/64
  const int nb = (blockIdx.x >> 2) * 64;  // 2048/64 -> grid 128
  const int tid = threadIdx.x;
  for (int i = tid; i < 4096; i += 256)
    tl[i >> 6][i & 63] = W[(kb + (i >> 6)) * 2048 + nb + (i & 63)];
  __syncthreads();
  for (int i = tid; i < 4096; i += 256) {
    const int n = i >> 6, k = i & 63;
    Wt[(nb + n) * 256 + kb + k] = f2bf(tl[k][n]);
  }
}

// ============================================================
// K1: s[b,t,r] = tanh(x[b,t,:] @ w1 + b1) @ w2 + b2
// ============================================================
__global__ __launch_bounds__(256) void k1_score(
    const float* __restrict__ x, const float* __restrict__ w1,
    const float* __restrict__ b1, const float* __restrict__ w2,
    const float* __restrict__ b2, float* __restrict__ s_out) {
  const int wave = threadIdx.x >> 6;
  const int lane = threadIdx.x & 63;
  for (int i = 0; i < 4; ++i) {
    const int bt = blockIdx.x * 16 + wave * 4 + i;  // grid=512 -> 8192 bt
    const float* xr = x + bt * DD;
    float acc = b1[lane];
    #pragma unroll 4
    for (int d = 0; d < DD; ++d)
      acc = fmaf(xr[d], w1[d * DA + lane], acc);
    const float a = tanhf(acc);
    #pragma unroll
    for (int r = 0; r < RR; ++r) {
      float v = a * w2[lane * RR + r];
      for (int off = 32; off > 0; off >>= 1) v += __shfl_xor(v, off);
      if (lane == 0) s_out[bt * RR + r] = v + b2[r];
    }
  }
}

// ============================================================
// K2: per (b,r): m=max_t s; e=exp(s-m); den=inclusive prefix sum
// ============================================================
__global__ __launch_bounds__(512) void k2_prefix(
    const float* __restrict__ s_in, float* __restrict__ e_out,
    float* __restrict__ inv_out) {
  const int b = blockIdx.x >> 3, r = blockIdx.x & 7;
  const int t = threadIdx.x;
  __shared__ float red[TT];
  __shared__ float buf[2][TT];
  const float v = s_in[(b * TT + t) * RR + r];
  red[t] = v;
  __syncthreads();
  for (int off = 256; off >= 1; off >>= 1) {
    if (t < off) red[t] = fmaxf(red[t], red[t + off]);
    __syncthreads();
  }
  const float m = red[0];
  const float e = expf(v - m);
  int p = 0;
  buf[0][t] = e;
  __syncthreads();
  for (int off = 1; off < TT; off <<= 1) {
    const float add = (t >= off) ? buf[p][t - off] : 0.f;
    buf[1 - p][t] = buf[p][t] + add;
    __syncthreads();
    p ^= 1;
  }
  const float den = buf[p][t];
  e_out[(b * TT + t) * RR + r] = e;
  inv_out[(b * TT + t) * RR + r] = 1.0f / den;
}

// ============================================================
// K3: M[b,t,d] scan -> emitted directly in bf16 for the MFMA k4
// ============================================================
__global__ __launch_bounds__(64) void k3_mix(
    const float* __restrict__ x, const float* __restrict__ e_in,
    const float* __restrict__ inv_in, ushort_t* __restrict__ Mout) {
  const int b = blockIdx.x >> 2;
  const int d = (blockIdx.x & 3) * 64 + threadIdx.x;
  __shared__ __align__(16) float el[TT * RR];
  __shared__ __align__(16) float il[TT * RR];
  for (int i = threadIdx.x * 4; i < TT * RR; i += 64 * 4) {
    *(float4*)&el[i] = *(const float4*)&e_in[b * TT * RR + i];
    *(float4*)&il[i] = *(const float4*)&inv_in[b * TT * RR + i];
  }
  __syncthreads();
  float4 c0 = {0.f, 0.f, 0.f, 0.f}, c1 = {0.f, 0.f, 0.f, 0.f};
  for (int t = 0; t < TT; ++t) {
    const float xv = x[(b * TT + t) * DD + d];
    const float4 e0 = *(const float4*)&el[t * RR];
    const float4 e1 = *(const float4*)&el[t * RR + 4];
    const float4 i0 = *(const float4*)&il[t * RR];
    const float4 i1 = *(const float4*)&il[t * RR + 4];
    c0.x = fmaf(e0.x, xv, c0.x); c0.y = fmaf(e0.y, xv, c0.y);
    c0.z = fmaf(e0.z, xv, c0.z); c0.w = fmaf(e0.w, xv, c0.w);
    c1.x = fmaf(e1.x, xv, c1.x); c1.y = fmaf(e1.y, xv, c1.y);
    c1.z = fmaf(e1.z, xv, c1.z); c1.w = fmaf(e1.w, xv, c1.w);
    float msum = c0.x * i0.x + c0.y * i0.y + c0.z * i0.z + c0.w * i0.w;
    msum += c1.x * i1.x + c1.y * i1.y + c1.z * i1.z + c1.w * i1.w;
    Mout[(b * TT + t) * DD + d] = f2bf(msum * 0.125f);
  }
}

// ============================================================
// K4 (MFMA): gates = Mb(8192x256 bf16) @ W_ih(bf16, via Wtb) + bias
// 128x128 tile, BK=32, 4 waves x (64x64), 16x16x32_bf16 MFMA.
// Verified layouts (guide m89/m91/m120): A[m=lane&15][k=quad*8+j],
// B[n=lane&15][k=quad*8+j], C/D col=lane&15 row=quad*4+reg.
// ============================================================
__global__ __launch_bounds__(256) void k4_mfma(
    const ushort_t* __restrict__ Mb, const ushort_t* __restrict__ Wtb,
    const float* __restrict__ bias, float* __restrict__ C) {
  const int bn = blockIdx.x & 15;
  const int bm = blockIdx.x >> 4;
  const int tid = threadIdx.x;
  const int wv = tid >> 6, lane = tid & 63;
  const int quad = lane >> 4, l16 = lane & 15;
  const int wm = (wv & 1) * 64, wn = (wv >> 1) * 64;
  const int row0 = bm * 128, col0 = bn * 128;

  __shared__ __align__(16) ushort_t As[128][40];  // [m][k], +8 pad
  __shared__ __align__(16) ushort_t Bs[128][40];  // [n][k], +8 pad

  f32x4 acc[4][4];
  #pragma unroll
  for (int i = 0; i < 4; ++i)
    #pragma unroll
    for (int j = 0; j < 4; ++j) acc[i][j] = (f32x4){0.f, 0.f, 0.f, 0.f};

  const int r = tid >> 1, koff = (tid & 1) * 16;
  for (int k0 = 0; k0 < 256; k0 += 32) {
    const uint4 av0 = *(const uint4*)&Mb[(row0 + r) * 256 + k0 + koff];
    const uint4 av1 = *(const uint4*)&Mb[(row0 + r) * 256 + k0 + koff + 8];
    const uint4 bv0 = *(const uint4*)&Wtb[(col0 + r) * 256 + k0 + koff];
    const uint4 bv1 = *(const uint4*)&Wtb[(col0 + r) * 256 + k0 + koff + 8];
    __syncthreads();
    *(uint4*)&As[r][koff] = av0; *(uint4*)&As[r][koff + 8] = av1;
    *(uint4*)&Bs[r][koff] = bv0; *(uint4*)&Bs[r][koff + 8] = bv1;
    __syncthreads();
    bf16x8 af[4], bfr[4];
    #pragma unroll
    for (int mi = 0; mi < 4; ++mi)
      af[mi] = *(const bf16x8*)&As[wm + mi * 16 + l16][quad * 8];
    #pragma unroll
    for (int ni = 0; ni < 4; ++ni)
      bfr[ni] = *(const bf16x8*)&Bs[wn + ni * 16 + l16][quad * 8];
    #pragma unroll
    for (int mi = 0; mi < 4; ++mi)
      #pragma unroll
      for (int ni = 0; ni < 4; ++ni)
        acc[mi][ni] = __builtin_amdgcn_mfma_f32_16x16x32_bf16(
            af[mi], bfr[ni], acc[mi][ni], 0, 0, 0);
  }
  #pragma unroll
  for (int ni = 0; ni < 4; ++ni) {
    const int col = col0 + wn + ni * 16 + l16;
    const float bv = bias[col];
    #pragma unroll
    for (int mi = 0; mi < 4; ++mi) {
      #pragma unroll
      for (int rg = 0; rg < 4; ++rg) {
        const int row = row0 + wm + mi * 16 + quad * 4 + rg;
        C[(long)row * 2048 + col] = acc[mi][ni][rg] + bv;
      }
    }
  }
}

// fast transcendentals: v_exp_f32 + v_rcp_f32 (~1e-6 err << tol)
__device__ __forceinline__ float fast_sigmoid(float x) {
  return __builtin_amdgcn_rcpf(1.f + __expf(-x));
}
__device__ __forceinline__ float fast_tanh(float x) {
  const float xc = fmaxf(x, -30.f);
  const float e = __expf(-2.f * xc);
  return (1.f - e) * __builtin_amdgcn_rcpf(1.f + e);
}

__device__ __forceinline__ unsigned long long poll_ld(
    const unsigned long long* p) {
  return __hip_atomic_load(p, __ATOMIC_RELAXED, __HIP_MEMORY_SCOPE_AGENT);
}

// ============================================================
// K5 v10: v9 + POLL PERMUTATION.
// v9 post-mortem: publishers (kq==0 lanes) issue publish+out stores
// right before their next poll; the poll's vmcnt(0) waits the publish
// ACK (~RT) -> publishers arrive ~300cyc late at the barrier EVERY
// step, and the barrier globalizes that to all 512 threads.
// Fix: thread polls unit pu=(j0+kq*32+cq)&511 (bijection). kq==0
// lanes poll the unit THEY just published (same-address FIFO through
// LLC -> satisfied in one sample; ack wait absorbed). Remote detects
// are carried by lanes with no same-step outstanding vmem.
// ============================================================
__global__ __launch_bounds__(512, 1) void k5_lstm(
    const float* __restrict__ gates, const float* __restrict__ whh,
    float* __restrict__ out, unsigned long long* hbuf) {
  const int s   = blockIdx.x & 15;       // unit-slice
  const int b   = blockIdx.x >> 4;       // batch = sync domain
  const int tid = threadIdx.x;           // 512 threads
  const int kq  = tid & 15;              // k-chunk: k in [kq*32, kq*32+32)
  const int cq  = tid >> 4;              // unit offset 0..31
  const int j0  = s * 32;
  const int unit = j0 + cq;
  // polled unit: self-first rotation (kq==0 -> own block's units)
  const int pu = (j0 + kq * 32 + cq) & 511;
  const int puslot = (pu >> 5) * 36 + (pu & 31);

  __shared__ __align__(16) float Wl[256 * 128];  // staging, 128 KB
  __shared__ __align__(16) float hl[2][576];     // parity; chunk*36+pos

  f2 wrA[32], wrB[32];
  for (int rnd = 0; rnd < 2; ++rnd) {
    for (int i = tid * 4; i < 256 * 128; i += 512 * 4) {
      const int k = i >> 7, c = i & 127;   // Wl[k][c], c = gate*32 + uo
      *(float4*)&Wl[i] =
          *(const float4*)&whh[(rnd * 256 + k) * G4H + (c >> 5) * HS + j0 + (c & 31)];
    }
    __syncthreads();
    if ((kq >> 3) == rnd) {
      const int kb = (kq & 7) * 32;
      #pragma unroll
      for (int kk = 0; kk < 32; ++kk) {
        const int base = (kb + kk) * 128 + cq;
        wrA[kk].x = *(volatile const float*)&Wl[base];
        wrA[kk].y = *(volatile const float*)&Wl[base + 32];
        wrB[kk].x = *(volatile const float*)&Wl[base + 64];
        wrB[kk].y = *(volatile const float*)&Wl[base + 96];
      }
    }
    __syncthreads();
  }

  float c_reg = 0.f;   // cell state (lives in lanes kq==0; unit j0+cq)

  // gates pipeline: g_cur = row t, g_n1 = row t+1 (kq==0 lanes only)
  float4 g_cur = {0, 0, 0, 0}, g_n1 = {0, 0, 0, 0};
  const float* gbase = gates + (long)b * TT * G4H + unit;
  if (kq == 0) {
    g_cur.x = gbase[0];            g_cur.y = gbase[HS];
    g_cur.z = gbase[2 * HS];       g_cur.w = gbase[3 * HS];
    const float* g1 = gbase + G4H;
    g_n1.x = g1[0];                g_n1.y = g1[HS];
    g_n1.z = g1[2 * HS];           g_n1.w = g1[3 * HS];
  }

  for (int t = 0; t < TT; ++t) {
    const int par = t & 1;
    if (t > 0) {
      // serial poll (one outstanding) of permuted unit pu (tag >= t)
      const unsigned long long* ha =
          hbuf + (((t - 1) & 1) * BB + b) * HS + pu;
      unsigned long long pkt;
      do {
        pkt = poll_ld(ha);
      } while ((unsigned)(pkt >> 32) < (unsigned)t);
      hl[par][puslot] = __uint_as_float((unsigned)pkt);
    }
    // issue gates row t+2 (>=1 full step old at the next vmcnt drain)
    float4 g_n2 = {0, 0, 0, 0};
    if (kq == 0) {
      const int tn = (t + 2 < TT) ? t + 2 : TT - 1;
      const float* g2 = gbase + (long)tn * G4H;
      g_n2.x = g2[0];        g_n2.y = g2[HS];
      g_n2.z = g2[2 * HS];   g_n2.w = g2[3 * HS];
    }
    // raw barrier: order LDS only; do NOT drain vmcnt
    __asm__ __volatile__("s_waitcnt lgkmcnt(0)\ns_barrier" ::: "memory");
    f2 acc01 = {0.f, 0.f}, acc23 = {0.f, 0.f};
    if (t > 0) {
      const float* hb = &hl[par][kq * 36];
      #pragma unroll
      for (int i = 0; i < 8; ++i) {
        const float4 h4 = *(const float4*)(hb + i * 4);
        const f2 hx = {h4.x, h4.x}, hy = {h4.y, h4.y};
        const f2 hz = {h4.z, h4.z}, hw = {h4.w, h4.w};
        acc01 += wrA[i * 4 + 0] * hx;  acc23 += wrB[i * 4 + 0] * hx;
        acc01 += wrA[i * 4 + 1] * hy;  acc23 += wrB[i * 4 + 1] * hy;
        acc01 += wrA[i * 4 + 2] * hz;  acc23 += wrB[i * 4 + 2] * hz;
        acc01 += wrA[i * 4 + 3] * hw;  acc23 += wrB[i * 4 + 3] * hw;
      }
    }
    #pragma unroll
    for (int off = 1; off <= 8; off <<= 1) {
      acc01.x += __shfl_xor(acc01.x, off);
      acc01.y += __shfl_xor(acc01.y, off);
      acc23.x += __shfl_xor(acc23.x, off);
      acc23.y += __shfl_xor(acc23.y, off);
    }
    if (kq == 0) {
      const float I = fast_sigmoid(acc01.x + g_cur.x);
      const float F = fast_sigmoid(acc01.y + g_cur.y);
      const float G = fast_tanh(acc23.x + g_cur.z);
      const float O = fast_sigmoid(acc23.y + g_cur.w);
      c_reg = F * c_reg + I * G;
      const float h = O * fast_tanh(c_reg);
      const unsigned long long pkt =
          ((unsigned long long)(unsigned)(t + 1) << 32) |
          (unsigned long long)__float_as_uint(h);
      __hip_atomic_store(&hbuf[(par * BB + b) * HS + unit], pkt,
                         __ATOMIC_RELAXED, __HIP_MEMORY_SCOPE_AGENT);
      out[((long)b * TT + t) * HS + unit] = h;   // hidden_seq
      if (t == TT - 1) {
        out[(long)BB * TT * HS + b * HS + unit] = h;               // h_t
        out[(long)BB * TT * HS + BB * HS + b * HS + unit] = c_reg; // c_t
      }
    }
    g_cur = g_n1;
    g_n1 = g_n2;
  }
}

// ============================================================
extern "C" void kernel_launch(void* const* d_in, const int* in_sizes, int n_in,
                              void* d_out, int out_size, void* d_ws,
                              size_t ws_size, hipStream_t stream) {
  const float* x    = (const float*)d_in[0];
  const float* w1   = (const float*)d_in[1];
  const float* b1   = (const float*)d_in[2];
  const float* w2   = (const float*)d_in[3];
  const float* b2   = (const float*)d_in[4];
  const float* wih  = (const float*)d_in[5];
  const float* whh  = (const float*)d_in[6];
  const float* bias = (const float*)d_in[7];
  float* out = (float*)d_out;

  float* ws = (float*)d_ws;
  float* s_buf  = ws;                       // dead after k2
  float* e_buf  = ws + 65536;
  float* i_buf  = ws + 131072;
  ushort_t* Mb  = (ushort_t*)(ws + 196608);   // bf16 M
  ushort_t* Wtb = (ushort_t*)(ws + 1245184);  // bf16 W_ih^T
  float* g_buf  = ws + 2293760;
  unsigned long long* hbuf64 = (unsigned long long*)ws;  // overlays s

  k0w_transpose<<<128, 256, 0, stream>>>(wih, Wtb);
  k1_score<<<512, 256, 0, stream>>>(x, w1, b1, w2, b2, s_buf);
  k2_prefix<<<BB * RR, 512, 0, stream>>>(s_buf, e_buf, i_buf);
  k3_mix<<<64, 64, 0, stream>>>(x, e_buf, i_buf, Mb);
  k4_mfma<<<64 * 16, 256, 0, stream>>>(Mb, Wtb, bias, g_buf);
  // zero packet tags (ws re-poisoned 0xAA each call); after k2's s reads
  hipMemsetAsync(hbuf64, 0, 2 * BB * HS * sizeof(unsigned long long), stream);
  k5_lstm<<<256, 512, 0, stream>>>(g_buf, whh, out, hbuf64);
}